// Round 7
// baseline (577.048 us; speedup 1.0000x reference)
//
#include <hip/hip_runtime.h>
#include <hip/hip_cooperative_groups.h>

namespace cg = cooperative_groups;

// DBASolver: B=16, N=196608, C=2.
// Single cooperative kernel: per-point depth coefficients (gdinv fp32 +
// sv[6] packed bf16) live in REGISTERS across grid.sync(); every block
// redundantly solves its batch's 6x6; depth written from the reg stash.
// Input read ONCE: 226 MB read + 12.6 MB write.
// R6: coop launch is ERROR-CHECKED (R5's silent failure) with a proven
// 3-kernel fallback; grid flattened to 1-D for coop-launch safety.

typedef float fv4 __attribute__((ext_vector_type(4)));
typedef float fv2 __attribute__((ext_vector_type(2)));

constexpr int NACC = 27;   // 21 upper-tri H entries + 6 g entries
constexpr int GX   = 48;   // blocks per batch -> 768 blocks total = 3/CU
constexpr int PPT  = 8;    // pairs per thread (48*256*8 = 98304 = N/2)

__device__ __forceinline__ uint32_t pack_bf2(float a, float b) {
    uint32_t ua = __float_as_uint(a);
    ua = (ua + 0x7FFFu + ((ua >> 16) & 1u)) >> 16;
    uint32_t ub = __float_as_uint(b);
    ub = (ub + 0x7FFFu + ((ub >> 16) & 1u)) >> 16;
    return ua | (ub << 16);
}
__device__ __forceinline__ float unpack_lo(uint32_t u) {
    return __uint_as_float(u << 16);
}
__device__ __forceinline__ float unpack_hi(uint32_t u) {
    return __uint_as_float(u & 0xFFFF0000u);
}

// Accumulate one point into A/g and emit its packed depth-coefficient stash.
__device__ __forceinline__ uint4 accum_point(
    const float* __restrict__ ja, const float* __restrict__ jb,
    float r0, float r1, float conf, float nlam, float jd0, float jd1,
    float lam, float* __restrict__ A, float* __restrict__ g)
{
    float h[6], gp[6];
#pragma unroll
    for (int i = 0; i < 6; ++i) {
        h[i]  = conf * (ja[i] * jd0 + jb[i] * jd1);   // H_pd[b,n,i]
        gp[i] = conf * (ja[i] * r0 + jb[i] * r1);
    }
    const float hdd = conf * (jd0 * jd0 + jd1 * jd1);
    const float inv = 1.0f / fmaxf(hdd + lam + nlam, 1e-4f);
    const float gd  = conf * (jd0 * r0 + jd1 * r1);
    const float gdinv = gd * inv;
    float sv[6];
#pragma unroll
    for (int i = 0; i < 6; ++i) sv[i] = h[i] * inv;
    int idx = 0;
#pragma unroll
    for (int i = 0; i < 6; ++i) {
#pragma unroll
        for (int j = i; j < 6; ++j) {
            A[idx] += conf * (ja[i] * ja[j] + jb[i] * jb[j]) - sv[i] * h[j];
            ++idx;
        }
        g[i] += gp[i] - h[i] * gdinv;
    }
    uint4 st;
    st.x = __float_as_uint(gdinv);
    st.y = pack_bf2(sv[0], sv[1]);
    st.z = pack_bf2(sv[2], sv[3]);
    st.w = pack_bf2(sv[4], sv[5]);
    return st;
}

__global__ __launch_bounds__(256, 3) void dba_fused(
    const float* __restrict__ r, const float* __restrict__ w,
    const float* __restrict__ J_p, const float* __restrict__ J_d,
    const float* __restrict__ lmbda, float* __restrict__ acc,
    float* __restrict__ pose_out, float* __restrict__ depth_out, int N)
{
    const int b  = blockIdx.x / GX;          // flattened 1-D grid
    const int bx = blockIdx.x - b * GX;
    const float lam = lmbda[b];
    const size_t base = (size_t)b * (size_t)N;
    const int tidb = bx * 256 + threadIdx.x;
    const int stride = GX * 256;

    float A[21], g[6];
#pragma unroll
    for (int i = 0; i < 21; ++i) A[i] = 0.f;
#pragma unroll
    for (int i = 0; i < 6; ++i) g[i] = 0.f;

    uint4 stash[2 * PPT];  // 64 VGPRs: packed depth coeffs, live across sync

#pragma unroll
    for (int k = 0; k < PPT; ++k) {
        const int pr = tidb + k * stride;
        const size_t p = base + ((size_t)pr << 1);
        const fv4 rv = *(const fv4*)(r + p * 2);
        const fv4 wv = *(const fv4*)(w + p * 2);
        const fv4 jd = *(const fv4*)(J_d + p * 2);
        const fv4* jp = (const fv4*)(J_p + p * 12);
        const fv4 q0 = jp[0];
        const fv4 q1 = jp[1];
        const fv4 q2 = jp[2];
        const fv4 q3 = jp[3];
        const fv4 q4 = jp[4];
        const fv4 q5 = jp[5];
        {
            const float ja[6] = {q0.x, q0.y, q0.z, q0.w, q1.x, q1.y};
            const float jb[6] = {q1.z, q1.w, q2.x, q2.y, q2.z, q2.w};
            stash[2 * k] = accum_point(ja, jb, rv.x, rv.y, wv.x, wv.y,
                                       jd.x, jd.y, lam, A, g);
        }
        {
            const float ja[6] = {q3.x, q3.y, q3.z, q3.w, q4.x, q4.y};
            const float jb[6] = {q4.z, q4.w, q5.x, q5.y, q5.z, q5.w};
            stash[2 * k + 1] = accum_point(ja, jb, rv.z, rv.w, wv.z, wv.w,
                                           jd.z, jd.w, lam, A, g);
        }
    }

    // block reduction of the 27 accumulators, then one atomic per entry
    float v[NACC];
#pragma unroll
    for (int i = 0; i < 21; ++i) v[i] = A[i];
#pragma unroll
    for (int i = 0; i < 6; ++i) v[21 + i] = g[i];
#pragma unroll
    for (int off = 32; off > 0; off >>= 1) {
#pragma unroll
        for (int i = 0; i < NACC; ++i) v[i] += __shfl_down(v[i], off, 64);
    }
    __shared__ float sred[4][NACC];
    const int wave = threadIdx.x >> 6;
    const int lane = threadIdx.x & 63;
    if (lane == 0) {
#pragma unroll
        for (int i = 0; i < NACC; ++i) sred[wave][i] = v[i];
    }
    __syncthreads();
    if (threadIdx.x < NACC) {
        const float s = sred[0][threadIdx.x] + sred[1][threadIdx.x] +
                        sred[2][threadIdx.x] + sred[3][threadIdx.x];
        atomicAdd(&acc[b * 32 + threadIdx.x], s);
    }

    cg::this_grid().sync();

    // every block redundantly solves its batch's 6x6 (thread 0, registers)
    __shared__ float sdp[6];
    if (threadIdx.x == 0) {
        float M[6][7];
        const float* a = acc + b * 32;
        int idx = 0;
#pragma unroll
        for (int i = 0; i < 6; ++i) {
#pragma unroll
            for (int j = i; j < 6; ++j) {
                const float t = a[idx++];
                M[i][j] = t;
                M[j][i] = t;
            }
        }
#pragma unroll
        for (int i = 0; i < 6; ++i) M[i][6] = a[21 + i];
#pragma unroll
        for (int i = 0; i < 6; ++i) M[i][i] += lam + 0.011f;
#pragma unroll
        for (int kk = 0; kk < 6; ++kk) {
            const float piv = 1.0f / M[kk][kk];
#pragma unroll
            for (int j = 0; j < 7; ++j) M[kk][j] *= piv;
#pragma unroll
            for (int i = 0; i < 6; ++i) {
                if (i == kk) continue;
                const float f = M[i][kk];
#pragma unroll
                for (int j = 0; j < 7; ++j) M[i][j] -= f * M[kk][j];
            }
        }
#pragma unroll
        for (int i = 0; i < 6; ++i) sdp[i] = M[i][6];
    }
    __syncthreads();

    if (bx == 0 && threadIdx.x < 6) {
        pose_out[b * 6 + threadIdx.x] =
            fminf(fmaxf(sdp[threadIdx.x], -2.0f), 2.0f);
    }

    const float dp0 = sdp[0], dp1 = sdp[1], dp2 = sdp[2];
    const float dp3 = sdp[3], dp4 = sdp[4], dp5 = sdp[5];

#pragma unroll
    for (int k = 0; k < PPT; ++k) {
        const int pr = tidb + k * stride;
        const size_t p = base + ((size_t)pr << 1);
        fv2 outv;
        {
            const uint4 st = stash[2 * k];
            outv.x = __uint_as_float(st.x) -
                     (unpack_lo(st.y) * dp0 + unpack_hi(st.y) * dp1 +
                      unpack_lo(st.z) * dp2 + unpack_hi(st.z) * dp3 +
                      unpack_lo(st.w) * dp4 + unpack_hi(st.w) * dp5);
        }
        {
            const uint4 st = stash[2 * k + 1];
            outv.y = __uint_as_float(st.x) -
                     (unpack_lo(st.y) * dp0 + unpack_hi(st.y) * dp1 +
                      unpack_lo(st.z) * dp2 + unpack_hi(st.z) * dp3 +
                      unpack_lo(st.w) * dp4 + unpack_hi(st.w) * dp5);
        }
        *(fv2*)(depth_out + p) = outv;
    }
}

// ---------- fallback: proven 3-kernel path ----------

__global__ __launch_bounds__(256) void dba_reduce_fb(
    const float* __restrict__ r, const float* __restrict__ w,
    const float* __restrict__ J_p, const float* __restrict__ J_d,
    const float* __restrict__ lmbda, float* __restrict__ acc, int N)
{
    const int b = blockIdx.y;
    const float lam = lmbda[b];
    float A[21], g[6];
#pragma unroll
    for (int i = 0; i < 21; ++i) A[i] = 0.f;
#pragma unroll
    for (int i = 0; i < 6; ++i) g[i] = 0.f;
    const size_t base = (size_t)b * (size_t)N;
    const int stride = gridDim.x * blockDim.x;
    for (int n = blockIdx.x * blockDim.x + threadIdx.x; n < N; n += stride) {
        const size_t p = base + n;
        const fv2 rv = *(const fv2*)(r + p * 2);
        const fv2 wv = *(const fv2*)(w + p * 2);
        const fv2 jd = *(const fv2*)(J_d + p * 2);
        const fv4* jp = (const fv4*)(J_p + p * 12);
        const fv4 q0 = jp[0];
        const fv4 q1 = jp[1];
        const fv4 q2 = jp[2];
        const float ja[6] = {q0.x, q0.y, q0.z, q0.w, q1.x, q1.y};
        const float jb[6] = {q1.z, q1.w, q2.x, q2.y, q2.z, q2.w};
        float h[6];
#pragma unroll
        for (int i = 0; i < 6; ++i) h[i] = wv.x * (ja[i] * jd.x + jb[i] * jd.y);
        const float hdd = wv.x * (jd.x * jd.x + jd.y * jd.y);
        const float inv = 1.0f / fmaxf(hdd + lam + wv.y, 1e-4f);
        const float gd  = wv.x * (jd.x * rv.x + jd.y * rv.y);
        const float gdinv = gd * inv;
        int idx = 0;
#pragma unroll
        for (int i = 0; i < 6; ++i) {
            const float hii = h[i] * inv;
#pragma unroll
            for (int j = i; j < 6; ++j) {
                A[idx] += wv.x * (ja[i] * ja[j] + jb[i] * jb[j]) - hii * h[j];
                ++idx;
            }
            g[i] += wv.x * (ja[i] * rv.x + jb[i] * rv.y) - h[i] * gdinv;
        }
    }
    float v[NACC];
#pragma unroll
    for (int i = 0; i < 21; ++i) v[i] = A[i];
#pragma unroll
    for (int i = 0; i < 6; ++i) v[21 + i] = g[i];
#pragma unroll
    for (int off = 32; off > 0; off >>= 1) {
#pragma unroll
        for (int i = 0; i < NACC; ++i) v[i] += __shfl_down(v[i], off, 64);
    }
    __shared__ float sred[4][NACC];
    const int wave = threadIdx.x >> 6;
    const int lane = threadIdx.x & 63;
    if (lane == 0) {
#pragma unroll
        for (int i = 0; i < NACC; ++i) sred[wave][i] = v[i];
    }
    __syncthreads();
    if (threadIdx.x < NACC) {
        const float s = sred[0][threadIdx.x] + sred[1][threadIdx.x] +
                        sred[2][threadIdx.x] + sred[3][threadIdx.x];
        atomicAdd(&acc[b * 32 + threadIdx.x], s);
    }
}

__global__ void dba_solve_fb(const float* __restrict__ acc,
                             const float* __restrict__ lmbda,
                             float* __restrict__ pose_out,
                             float* __restrict__ dp_ws, int B)
{
    const int b = blockIdx.x * blockDim.x + threadIdx.x;
    if (b >= B) return;
    float M[6][7];
    const float* a = acc + b * 32;
    int idx = 0;
#pragma unroll
    for (int i = 0; i < 6; ++i) {
#pragma unroll
        for (int j = i; j < 6; ++j) {
            const float t = a[idx++];
            M[i][j] = t;
            M[j][i] = t;
        }
    }
#pragma unroll
    for (int i = 0; i < 6; ++i) M[i][6] = a[21 + i];
    const float lam = lmbda[b];
#pragma unroll
    for (int i = 0; i < 6; ++i) M[i][i] += lam + 0.011f;
#pragma unroll
    for (int k = 0; k < 6; ++k) {
        const float piv = 1.0f / M[k][k];
#pragma unroll
        for (int j = 0; j < 7; ++j) M[k][j] *= piv;
#pragma unroll
        for (int i = 0; i < 6; ++i) {
            if (i == k) continue;
            const float f = M[i][k];
#pragma unroll
            for (int j = 0; j < 7; ++j) M[i][j] -= f * M[k][j];
        }
    }
#pragma unroll
    for (int i = 0; i < 6; ++i) {
        const float x = M[i][6];
        dp_ws[b * 6 + i] = x;
        pose_out[b * 6 + i] = fminf(fmaxf(x, -2.0f), 2.0f);
    }
}

__global__ __launch_bounds__(256) void dba_depth_fb(
    const float* __restrict__ r, const float* __restrict__ w,
    const float* __restrict__ J_p, const float* __restrict__ J_d,
    const float* __restrict__ lmbda, const float* __restrict__ dp_ws,
    float* __restrict__ depth_out, int N)
{
    const int b = blockIdx.y;
    const float lam = lmbda[b];
    float dp[6];
#pragma unroll
    for (int i = 0; i < 6; ++i) dp[i] = dp_ws[b * 6 + i];
    const size_t base = (size_t)b * (size_t)N;
    const int stride = gridDim.x * blockDim.x;
    for (int n = blockIdx.x * blockDim.x + threadIdx.x; n < N; n += stride) {
        const size_t p = base + n;
        const fv2 rv = *(const fv2*)(r + p * 2);
        const fv2 wv = *(const fv2*)(w + p * 2);
        const fv2 jd = *(const fv2*)(J_d + p * 2);
        const fv4* jp = (const fv4*)(J_p + p * 12);
        const fv4 q0 = jp[0];
        const fv4 q1 = jp[1];
        const fv4 q2 = jp[2];
        const float ja[6] = {q0.x, q0.y, q0.z, q0.w, q1.x, q1.y};
        const float jb[6] = {q1.z, q1.w, q2.x, q2.y, q2.z, q2.w};
        float vsum = 0.f;
#pragma unroll
        for (int i = 0; i < 6; ++i)
            vsum += (ja[i] * jd.x + jb[i] * jd.y) * dp[i];
        vsum *= wv.x;
        const float hdd = wv.x * (jd.x * jd.x + jd.y * jd.y);
        const float inv = 1.0f / fmaxf(hdd + lam + wv.y, 1e-4f);
        const float gd  = wv.x * (jd.x * rv.x + jd.y * rv.y);
        depth_out[p] = inv * (gd - vsum);
    }
}

extern "C" void kernel_launch(void* const* d_in, const int* in_sizes, int n_in,
                              void* d_out, int out_size, void* d_ws, size_t ws_size,
                              hipStream_t stream)
{
    const float* r   = (const float*)d_in[0];
    const float* w   = (const float*)d_in[1];
    const float* J_p = (const float*)d_in[2];
    const float* J_d = (const float*)d_in[3];
    const float* lmb = (const float*)d_in[4];
    const int B = in_sizes[4];            // 16
    const int N = in_sizes[0] / (B * 2);  // 196608

    float* acc   = (float*)d_ws;           // B*32 accumulators
    float* dp_ws = (float*)d_ws + B * 32;  // fallback: B*6 unclipped dp
    float* out   = (float*)d_out;
    float* pose  = out;
    float* depth = out + B * 6;

    (void)hipMemsetAsync(acc, 0, B * 32 * sizeof(float), stream);

    hipError_t cerr = hipErrorUnknown;
    if ((N >> 1) == GX * 256 * PPT) {
        void* args[] = {(void*)&r, (void*)&w, (void*)&J_p, (void*)&J_d,
                        (void*)&lmb, (void*)&acc, (void*)&pose, (void*)&depth,
                        (void*)&N};
        cerr = hipLaunchCooperativeKernel((void*)dba_fused, dim3(GX * B),
                                          dim3(256), args, 0, stream);
    }
    if (cerr != hipSuccess) {
        dim3 grid(192, B);
        dba_reduce_fb<<<grid, 256, 0, stream>>>(r, w, J_p, J_d, lmb, acc, N);
        dba_solve_fb<<<1, 64, 0, stream>>>(acc, lmb, pose, dp_ws, B);
        dba_depth_fb<<<grid, 256, 0, stream>>>(r, w, J_p, J_d, lmb, dp_ws,
                                               depth, N);
    }
}